// Round 1
// 373.815 us; speedup vs baseline: 1.0061x; 1.0061x over previous
//
#include <hip/hip_runtime.h>

// FastfoodProjection: out = (1/8192) * H * diag(G) * P * H * diag(B) * pad(x)
// per row; H = Hadamard_8192, x rows of 4096 padded to 8192, out rows 8192.
//
// v2: 512 threads/block, 16 elements/thread (r = 2m + e, bit 0 of logical
// index j always in e => all LDS exchanges are float2/b64). Halving per-thread
// state (v[16]+q[8] ~= 56 VGPR) targets <=64 VGPR => 8 waves/SIMD, 32 waves/CU
// (2x the 256-thread/32-reg version, which needed >64 VGPR and ran at 50%
// occupancy). Cost: 4 register phases per FWHT instead of 3 (7 LDS roundtrips
// vs 5, ~48 us of LDS pipe vs 37 — both under the ~64 us HBM floor), 8
// barriers vs 6. The previous version was stall-bound (~6x off every pipe
// roofline), so occupancy is the lever.
//
// Four register phases per FWHT (4 j-bits each, bit 0 shared):
//   A: j = m*1024 + 2t + e              bits {0, 10..12}  (global I/O layout)
//   B: j = t*16   + 2m + e              bits {1..3}
//   C: j = (t>>3)*128 + m*16 + (t&7)*2 + e    bits {4..6}
//   D: j = (t>>6)*1024 + m*128 + (t&63)*2 + e bits {7..9} (0 passive on FWHT2)
// FWHT1 runs A->B->C->D, permutation gather lands directly in layout D,
// FWHT2 runs D->C->B->A so stores are fully contiguous (512 B per wave instr).
// Layouts partition j by thread, so read-X -> write-X (same layout) needs NO
// barrier: 8 __syncthreads total.
// LDS pad +2 words per 32 keeps every phase's b64 pattern conflict-free
// (each bank hit exactly 4x per wave access = 512B/4cyc minimum) and
// preserves 8 B alignment. Padded bases fold to base + constant*m so each
// phase needs ONE address register + 16-bit ds immediate offsets.

constexpr int N  = 8192;
constexpr int NT = 512;
constexpr int NR = 16;
constexpr int LDS_WORDS = N + 2 * (N / 32); // 8704 words = 34 KB

__device__ __forceinline__ int padw(int w) { return w + 2 * (w >> 5); }

template <int FIRST_MASK>
__device__ __forceinline__ void butterfly(float v[NR]) {
    #pragma unroll
    for (int b = FIRST_MASK; b < NR; b <<= 1) {
        #pragma unroll
        for (int r = 0; r < NR; ++r) {
            if ((r & b) == 0) {
                float a = v[r], c = v[r ^ b];
                v[r]     = a + c;
                v[r ^ b] = a - c;
            }
        }
    }
}

// __launch_bounds__(512, 8): 8 waves/SIMD min => compiler caps VGPR <= 64,
// giving 32 waves/CU; LDS limits us to 4 blocks/CU (4 x 34 KB = 136 KB).
__global__ __launch_bounds__(NT, 8) void fastfood_kernel(
    const float* __restrict__ x, const float* __restrict__ Bv,
    const float* __restrict__ Gv, const int* __restrict__ perm,
    float* __restrict__ out)
{
    __shared__ float lds[LDS_WORDS];
    const int t = threadIdx.x;
    const int row = blockIdx.x;
    const float* xrow = x + (size_t)row * 4096;

    // unpadded j-bases (for global addresses) and padded LDS word bases.
    // padw(base + stride*m) folds to pbase + pstride*m for each layout:
    //   A/D: stride 1024 -> pstride 1088;  B: 2 -> 2 (within 16-word window);
    //   C: 16 -> 16 + 2*(m>>1);            (all verified against padw()).
    const int wA = 2 * t;                                   // + m*1024
    const int pA = 2 * t + 2 * (t >> 4);
    const int pB = 16 * t + 2 * (t >> 1);                   // + 2m
    const int wD = (t >> 6) * 1024 + (t & 63) * 2;          // + m*128
    const int pD = (t >> 6) * 1088 + (t & 63) * 2 + 2 * ((t & 63) >> 4);
    const int pC = (t >> 3) * 136 + (t & 7) * 2;            // + m*16 + 2*(m>>1)

    float v[NR];

    // ---- load + B multiply, layout A (j < 4096 <=> m < 4)
    #pragma unroll
    for (int m = 0; m < 4; ++m) {
        int j = m * 1024 + wA;
        float2 xv = *(const float2*)(xrow + j);
        float2 bv = *(const float2*)(Bv + j);
        v[2 * m]     = xv.x * bv.x;
        v[2 * m + 1] = xv.y * bv.y;
    }
    #pragma unroll
    for (int m = 4; m < 8; ++m) { v[2 * m] = 0.f; v[2 * m + 1] = 0.f; }

    // ---- FWHT #1: phase A (bits 0, 10..12)
    butterfly<1>(v);
    #pragma unroll
    for (int m = 0; m < 8; ++m)
        *(float2*)&lds[pA + 1088 * m] = make_float2(v[2 * m], v[2 * m + 1]);
    __syncthreads();

    // phase B (bits 1..3)
    #pragma unroll
    for (int m = 0; m < 8; ++m) {
        float2 d = *(const float2*)&lds[pB + 2 * m];
        v[2 * m] = d.x; v[2 * m + 1] = d.y;
    }
    butterfly<2>(v);
    #pragma unroll
    for (int m = 0; m < 8; ++m)   // same addresses we read: no barrier needed
        *(float2*)&lds[pB + 2 * m] = make_float2(v[2 * m], v[2 * m + 1]);
    __syncthreads();

    // phase C (bits 4..6)
    #pragma unroll
    for (int m = 0; m < 8; ++m) {
        float2 d = *(const float2*)&lds[pC + 16 * m + 2 * (m >> 1)];
        v[2 * m] = d.x; v[2 * m + 1] = d.y;
    }
    butterfly<2>(v);
    #pragma unroll
    for (int m = 0; m < 8; ++m)   // same addresses we read: no barrier needed
        *(float2*)&lds[pC + 16 * m + 2 * (m >> 1)] = make_float2(v[2 * m], v[2 * m + 1]);
    __syncthreads();

    // phase D (bits 7..9); prefetch perm (layout-D indices) to hide L2 latency
    #pragma unroll
    for (int m = 0; m < 8; ++m) {
        float2 d = *(const float2*)&lds[pD + 136 * m];
        v[2 * m] = d.x; v[2 * m + 1] = d.y;
    }
    int2 q[8];
    #pragma unroll
    for (int m = 0; m < 8; ++m)
        q[m] = *(const int2*)(perm + wD + 128 * m);
    butterfly<2>(v);
    #pragma unroll
    for (int m = 0; m < 8; ++m)   // same addresses we read: no barrier needed
        *(float2*)&lds[pD + 136 * m] = make_float2(v[2 * m], v[2 * m + 1]);
    __syncthreads();

    // ---- permutation gather + G multiply, landing in layout D
    #pragma unroll
    for (int m = 0; m < 8; ++m) {
        float2 g = *(const float2*)(Gv + wD + 128 * m);
        v[2 * m]     = lds[q[m].x + 2 * (q[m].x >> 5)] * g.x;
        v[2 * m + 1] = lds[q[m].y + 2 * (q[m].y >> 5)] * g.y;
    }

    // ---- FWHT #2: phase D (bits 0, 7..9) — butterfly before the barrier
    butterfly<1>(v);
    __syncthreads();               // all random gathers done before overwrite
    #pragma unroll
    for (int m = 0; m < 8; ++m)
        *(float2*)&lds[pD + 136 * m] = make_float2(v[2 * m], v[2 * m + 1]);
    __syncthreads();

    // phase C (bits 4..6)
    #pragma unroll
    for (int m = 0; m < 8; ++m) {
        float2 d = *(const float2*)&lds[pC + 16 * m + 2 * (m >> 1)];
        v[2 * m] = d.x; v[2 * m + 1] = d.y;
    }
    butterfly<2>(v);
    #pragma unroll
    for (int m = 0; m < 8; ++m)   // same addresses we read: no barrier needed
        *(float2*)&lds[pC + 16 * m + 2 * (m >> 1)] = make_float2(v[2 * m], v[2 * m + 1]);
    __syncthreads();

    // phase B (bits 1..3)
    #pragma unroll
    for (int m = 0; m < 8; ++m) {
        float2 d = *(const float2*)&lds[pB + 2 * m];
        v[2 * m] = d.x; v[2 * m + 1] = d.y;
    }
    butterfly<2>(v);
    #pragma unroll
    for (int m = 0; m < 8; ++m)   // same addresses we read: no barrier needed
        *(float2*)&lds[pB + 2 * m] = make_float2(v[2 * m], v[2 * m + 1]);
    __syncthreads();

    // phase A (bits 10..12)
    #pragma unroll
    for (int m = 0; m < 8; ++m) {
        float2 d = *(const float2*)&lds[pA + 1088 * m];
        v[2 * m] = d.x; v[2 * m + 1] = d.y;
    }
    butterfly<2>(v);

    // ---- store, fully coalesced (512 B per wave instruction), scale folded
    const float scale = 1.0f / 8192.0f;
    float* orow = out + (size_t)row * 8192;
    #pragma unroll
    for (int m = 0; m < 8; ++m) {
        int j = m * 1024 + wA;
        *(float2*)(orow + j) = make_float2(v[2 * m] * scale, v[2 * m + 1] * scale);
    }
}

extern "C" void kernel_launch(void* const* d_in, const int* in_sizes, int n_in,
                              void* d_out, int out_size, void* d_ws, size_t ws_size,
                              hipStream_t stream) {
    const float* x    = (const float*)d_in[0];
    const float* Bv   = (const float*)d_in[1];
    const float* Gv   = (const float*)d_in[2];
    const int*   perm = (const int*)d_in[3];
    float* out = (float*)d_out;
    fastfood_kernel<<<dim3(8192), dim3(NT), 0, stream>>>(x, Bv, Gv, perm, out);
}